// Round 13
// baseline (98.012 us; speedup 1.0000x reference)
//
#include <hip/hip_runtime.h>
#include <stdint.h>

#define D_IN 2048
#define D_H  512
#define BM   64
#define NST  16   // stages of 128 k

typedef __attribute__((ext_vector_type(4)))  int i32x4;
typedef __attribute__((ext_vector_type(16))) int i32x16;

// Wfrag[sg][t][l][16] : byte j = sign(W[sg*32 + 16*(l>>5) + j][t*32 + (l&31)])
// -> every GEMM B-load is 64 lanes x 16B = 1KB contiguous.
__global__ __launch_bounds__(1024) void pack_wt_kernel(
    const float* __restrict__ W, char* __restrict__ Wf) {
  const int s = blockIdx.x;          // 0..63  (k-step)
  const int t = threadIdx.x >> 6;    // 0..15  (col tile)
  const int l = threadIdx.x & 63;    // lane
  const int n = t * 32 + (l & 31);
  const int kbase = s * 32 + 16 * (l >> 5);
  uint wq[4];
#pragma unroll
  for (int q = 0; q < 4; ++q) {
    uint w = 0x01010101u;  // +1 bytes; negative -> XOR 0xFE -> 0xFF (-1)
#pragma unroll
    for (int j = 0; j < 4; ++j) {
      uint bits = __float_as_uint(W[(size_t)(kbase + 4 * q + j) * D_H + n]);
      w ^= ((uint)((int)bits >> 31)) & (0xFEu << (8 * j));
    }
    wq[q] = w;
  }
  *(uint4*)(Wf + ((size_t)(s * 16 + t) * 64 + l) * 16) =
      make_uint4(wq[0], wq[1], wq[2], wq[3]);
}

__device__ __forceinline__ uint pack4(float4 v) {
  uint w = 0x01010101u;
  w ^= ((uint)((int)__float_as_uint(v.x) >> 31)) & 0x000000FEu;
  w ^= ((uint)((int)__float_as_uint(v.y) >> 31)) & 0x0000FE00u;
  w ^= ((uint)((int)__float_as_uint(v.z) >> 31)) & 0x00FE0000u;
  w ^= ((uint)((int)__float_as_uint(v.w) >> 31)) & 0xFE000000u;
  return w;
}

// Binary GEMM via v_mfma_i32_32x32x32_i8.
// Block: 1024 thr / 16 waves, 64 rows x 512 cols (X read once). Wave wv owns
// ONE col tile [32wv, 32wv+32) x all 64 rows: 2 MFMA per k-step, acc = 2 x
// i32x16 (32 regs). Total live ~80 regs -> 16-wave block resident at 4
// waves/SIMD (2x R10's occupancy).
// Per stage (128 k): 4 B-loads (1KB contig, oldest in vmcnt) -> 2 X-loads
// for st+1 (youngest; depth-1) -> 4 k-steps {2 ds_read_b128, 2 MFMA} ->
// pack X -> 2 ds_write_b32 -> barrier. B-waits never touch the X prefetch.
// LDS: frag-linear A tiles, frag(mt,s) at (mt*4+s)*1024 + lane*16
// (read conflict-free; write 4-way, minor).
__global__ __launch_bounds__(1024) void bgemm_kernel(
    const float* __restrict__ X, const char* __restrict__ Wf,
    const float* __restrict__ b, const float* __restrict__ beta,
    const float* __restrict__ mm, const float* __restrict__ mv,
    float* __restrict__ out) {
  __shared__ __align__(16) char XpL[2][8192];  // 2 x (8 frags x 1024 B)

  const int tid = threadIdx.x;
  const int l   = tid & 63;
  const int wv  = tid >> 6;        // 0..15
  const int am  = l & 31;
  const int ah  = l >> 5;
  const size_t m0 = (size_t)blockIdx.x * BM;
  const int cb  = wv * 32;         // wave's col-tile base

  // X loader: thread -> row xr = tid>>4 (0..63), chunks c0 = tid&15 and c0+16
  const int xr = tid >> 4;
  const int c0 = tid & 15;
  const float4* X4row = (const float4*)(X + (m0 + xr) * D_IN);

  // LDS write byte offset for chunk c (k-bytes 4c..4c+4 of row xr):
  // frag = (xr>>5)*4 + (c>>3); lane slot = (xr&31) + 32*((c>>2)&1); byte 4*(c&3)
  const int ws0 = ((xr >> 5) * 4 + (c0 >> 3)) * 1024
                + ((xr & 31) + 32 * ((c0 >> 2) & 1)) * 16 + 4 * (c0 & 3);
  const int ws1 = ws0 + 2048;  // chunk c0+16: frag +2, all else identical

  // A read: frag(mt,s) at mt*4096 + s*1024 + l*16
  const int alane = l * 16;

  // B: wave's tile = wv; frag (st,s) at + (st*4+s)*16384
  const char* Bb = Wf + (size_t)wv * 1024 + (size_t)l * 16;

  i32x16 acc0, acc1;  // row-halves 0..31 / 32..63
#pragma unroll
  for (int r = 0; r < 16; ++r) { acc0[r] = 0; acc1[r] = 0; }

  float4 vx0, vx1;  // depth-1 X prefetch (single set, R10-style)

  // ---- prologue: X(0) packed directly into buf0 ----
  vx0 = X4row[c0];
  vx1 = X4row[c0 + 16];
  *(uint*)(&XpL[0][0] + ws0) = pack4(vx0);
  *(uint*)(&XpL[0][0] + ws1) = pack4(vx1);
  __syncthreads();

#pragma unroll 1
  for (int st = 0; st < NST; ++st) {
    const size_t so = (size_t)st * 65536;
    // 1) B loads (oldest in vmcnt)
    i32x4 B0 = *(const i32x4*)(Bb + so);
    i32x4 B1 = *(const i32x4*)(Bb + so + 16384);
    i32x4 B2 = *(const i32x4*)(Bb + so + 32768);
    i32x4 B3 = *(const i32x4*)(Bb + so + 49152);
    // 2) X for stage st+1 (youngest; consumed at stage end)
    if (st + 1 < NST) {
      vx0 = X4row[(st + 1) * 32 + c0];
      vx1 = X4row[(st + 1) * 32 + c0 + 16];
    }
    // 3) 4 k-steps: 2 conflict-free ds_read_b128 + 2 MFMA each
    const char* buf = &XpL[st & 1][0];
    {
      i32x4 a0 = *(const i32x4*)(buf + 0 * 1024 + alane);
      i32x4 a1 = *(const i32x4*)(buf + 4096 + 0 * 1024 + alane);
      acc0 = __builtin_amdgcn_mfma_i32_32x32x32_i8(a0, B0, acc0, 0, 0, 0);
      acc1 = __builtin_amdgcn_mfma_i32_32x32x32_i8(a1, B0, acc1, 0, 0, 0);
    }
    {
      i32x4 a0 = *(const i32x4*)(buf + 1 * 1024 + alane);
      i32x4 a1 = *(const i32x4*)(buf + 4096 + 1 * 1024 + alane);
      acc0 = __builtin_amdgcn_mfma_i32_32x32x32_i8(a0, B1, acc0, 0, 0, 0);
      acc1 = __builtin_amdgcn_mfma_i32_32x32x32_i8(a1, B1, acc1, 0, 0, 0);
    }
    {
      i32x4 a0 = *(const i32x4*)(buf + 2 * 1024 + alane);
      i32x4 a1 = *(const i32x4*)(buf + 4096 + 2 * 1024 + alane);
      acc0 = __builtin_amdgcn_mfma_i32_32x32x32_i8(a0, B2, acc0, 0, 0, 0);
      acc1 = __builtin_amdgcn_mfma_i32_32x32x32_i8(a1, B2, acc1, 0, 0, 0);
    }
    {
      i32x4 a0 = *(const i32x4*)(buf + 3 * 1024 + alane);
      i32x4 a1 = *(const i32x4*)(buf + 4096 + 3 * 1024 + alane);
      acc0 = __builtin_amdgcn_mfma_i32_32x32x32_i8(a0, B3, acc0, 0, 0, 0);
      acc1 = __builtin_amdgcn_mfma_i32_32x32x32_i8(a1, B3, acc1, 0, 0, 0);
    }
    // 4) pack + write next stage's A tile (X issued one full stage ago)
    if (st + 1 < NST) {
      char* nbuf = &XpL[(st + 1) & 1][0];
      *(uint*)(nbuf + ws0) = pack4(vx0);
      *(uint*)(nbuf + ws1) = pack4(vx1);
    }
    __syncthreads();
  }

  // ---- epilogue: out = (dot + b - mean) * rsqrt(var+eps) + beta ----
  // D layout (verified R7-R12): col = cb + am, row = (r&3)+8*(r>>2)+4*ah (+32mt)
  const int rb = 4 * ah;
  const int c  = cb + am;
  const float bb  = b[c];
  const float mmc = mm[c];
  const float bec = beta[c];
  const float inv = rsqrtf(mv[c] + 1e-3f);
#pragma unroll
  for (int mt = 0; mt < 2; ++mt) {
    const i32x16 A = (mt == 0) ? acc0 : acc1;
#pragma unroll
    for (int r = 0; r < 16; ++r) {
      const int row = (r & 3) + 8 * (r >> 2) + rb + 32 * mt;
      out[(m0 + row) * D_H + c] = ((float)A[r] + bb - mmc) * inv + bec;
    }
  }
}

extern "C" void kernel_launch(void* const* d_in, const int* in_sizes, int n_in,
                              void* d_out, int out_size, void* d_ws, size_t ws_size,
                              hipStream_t stream) {
  const float* X    = (const float*)d_in[0];  // [32768, 2048]
  const float* W    = (const float*)d_in[1];  // [2048, 512]
  const float* b    = (const float*)d_in[2];  // [512]
  const float* beta = (const float*)d_in[3];  // [512]
  const float* mm   = (const float*)d_in[4];  // [512]
  const float* mv   = (const float*)d_in[5];  // [512]
  float* out = (float*)d_out;                 // [32768, 512]

  char* Wf = (char*)d_ws;  // frag-ordered W signs, 1 MB

  pack_wt_kernel<<<dim3(D_IN / 32), dim3(1024), 0, stream>>>(W, Wf);

  const int M = in_sizes[0] / D_IN;  // 32768
  bgemm_kernel<<<dim3(M / BM), dim3(1024), 0, stream>>>(X, Wf, b, beta, mm, mv, out);
}

// Round 14
// 92.334 us; speedup vs baseline: 1.0615x; 1.0615x over previous
//
#include <hip/hip_runtime.h>
#include <stdint.h>

#define D_IN 2048
#define D_H  512
#define BM   64
#define NST  32   // stages of 64 k

typedef __attribute__((ext_vector_type(4)))  int i32x4;
typedef __attribute__((ext_vector_type(16))) int i32x16;

// Raw barrier: LDS-only drain (lgkmcnt(0)), vmcnt NOT drained -> global
// prefetch loads stay in flight across the barrier (the hipcc __syncthreads
// lowering drains vmcnt(0) too, which empties the HBM queue every stage).
__device__ __forceinline__ void barrier_lgkm_only() {
  asm volatile("s_waitcnt lgkmcnt(0)" ::: "memory");
  __builtin_amdgcn_sched_barrier(0);
  __builtin_amdgcn_s_barrier();
  __builtin_amdgcn_sched_barrier(0);
}

// Wfrag[sg][t][l][16] : byte j = sign(W[sg*32 + 16*(l>>5) + j][t*32 + (l&31)])
// -> every GEMM B-load is 64 lanes x 16B = 1KB contiguous.
__global__ __launch_bounds__(1024) void pack_wt_kernel(
    const float* __restrict__ W, char* __restrict__ Wf) {
  const int s = blockIdx.x;          // 0..63  (k-step)
  const int t = threadIdx.x >> 6;    // 0..15  (col tile)
  const int l = threadIdx.x & 63;    // lane
  const int n = t * 32 + (l & 31);
  const int kbase = s * 32 + 16 * (l >> 5);
  uint wq[4];
#pragma unroll
  for (int q = 0; q < 4; ++q) {
    uint w = 0x01010101u;  // +1 bytes; negative -> XOR 0xFE -> 0xFF (-1)
#pragma unroll
    for (int j = 0; j < 4; ++j) {
      uint bits = __float_as_uint(W[(size_t)(kbase + 4 * q + j) * D_H + n]);
      w ^= ((uint)((int)bits >> 31)) & (0xFEu << (8 * j));
    }
    wq[q] = w;
  }
  *(uint4*)(Wf + ((size_t)(s * 16 + t) * 64 + l) * 16) =
      make_uint4(wq[0], wq[1], wq[2], wq[3]);
}

__device__ __forceinline__ uint pack4(float4 v) {
  uint w = 0x01010101u;
  w ^= ((uint)((int)__float_as_uint(v.x) >> 31)) & 0x000000FEu;
  w ^= ((uint)((int)__float_as_uint(v.y) >> 31)) & 0x0000FE00u;
  w ^= ((uint)((int)__float_as_uint(v.z) >> 31)) & 0x00FE0000u;
  w ^= ((uint)((int)__float_as_uint(v.w) >> 31)) & 0xFE000000u;
  return w;
}

// Binary GEMM via v_mfma_i32_32x32x32_i8. Structure = R12 (refcheck'd):
// 512 thr / 8 waves, 64 rows x 512 cols, wave owns 2 col tiles, acc 64 regs.
// 64k stages, depth-2 X prefetch (named P0/P1), early pack of X(st+1).
// NEW: lgkm-only raw barriers -> X(st+1)+X(st+2) (2 stages of loads) remain
// in flight across every barrier; per-CU load queue never empties.
__global__ __launch_bounds__(512) void bgemm_kernel(
    const float* __restrict__ X, const char* __restrict__ Wf,
    const float* __restrict__ b, const float* __restrict__ beta,
    const float* __restrict__ mm, const float* __restrict__ mv,
    float* __restrict__ out) {
  __shared__ __align__(16) char XpL[2][4096];  // 2 x (2mt x 2s x 64 lanes x 16B)

  const int tid = threadIdx.x;
  const int l   = tid & 63;
  const int wv  = tid >> 6;        // 0..7
  const int am  = l & 31;
  const int ah  = l >> 5;
  const size_t m0 = (size_t)blockIdx.x * BM;
  const int colbase = wv * 64;

  // X loader: thread -> row = tid>>3 (0..63), chunks c0 = tid&7 and c0+8
  const int xrow = tid >> 3;
  const int c0   = tid & 7;
  const float4* X4row = (const float4*)(X + (m0 + xrow) * D_IN);

  // LDS write byte offsets (linear frag layout; second chunk at +1024)
  const int ws0 = (xrow >> 5) * 2048 + (((xrow & 31) + 32 * ((c0 >> 2) & 1)) << 4)
                  + 4 * (c0 & 3);

  // LDS read: frag addr = mt*2048 + s*1024 + l*16
  const int alane = l * 16;

  // B pointers: Wf[sg][tile][l][16]; per stage sg0 = 2*st -> +st*32768
  const char* Bb0 = Wf + (size_t)(2 * wv) * 1024 + (size_t)l * 16;
  const char* Bb1 = Bb0 + 1024;

  i32x16 acc00, acc01, acc10, acc11;  // [rowhalf mt][tile]
#pragma unroll
  for (int r = 0; r < 16; ++r) { acc00[r] = 0; acc01[r] = 0; acc10[r] = 0; acc11[r] = 0; }

  float4 P0a, P0b, P1a, P1b;  // depth-2 X prefetch (named, parity-tied)

  // ---- prologue: X(0) -> buf0 directly; X(1) -> P1 ----
  P0a = X4row[c0];
  P0b = X4row[c0 + 8];
  P1a = X4row[16 + c0];
  P1b = X4row[16 + c0 + 8];
  *(uint*)(XpL[0] + ws0)        = pack4(P0a);
  *(uint*)(XpL[0] + ws0 + 1024) = pack4(P0b);
  barrier_lgkm_only();

  // even stage: pack Pc=P1 (X(st+1)), prefetch Pn=P0 <- X(st+2); odd: swap.
#define STAGE_BODY(ST, Pca, Pcb, Pna, Pnb, PREF, PACKN)                      \
  do {                                                                       \
    const size_t so = (size_t)(ST) * 32768;                                  \
    i32x4 B00 = *(const i32x4*)(Bb0 + so);            /* s=0, tile0 */       \
    i32x4 B01 = *(const i32x4*)(Bb1 + so);            /* s=0, tile1 */       \
    i32x4 B10 = *(const i32x4*)(Bb0 + so + 16384);    /* s=1, tile0 */       \
    i32x4 B11 = *(const i32x4*)(Bb1 + so + 16384);    /* s=1, tile1 */       \
    if (PREF) {                                                              \
      Pna = X4row[((ST) + 2) * 16 + c0];                                     \
      Pnb = X4row[((ST) + 2) * 16 + c0 + 8];                                 \
    }                                                                        \
    if (PACKN) { /* X(st+1): issued a full stage ago */                      \
      char* nbuf = &XpL[((ST) + 1) & 1][0];                                  \
      *(uint*)(nbuf + ws0)        = pack4(Pca);                              \
      *(uint*)(nbuf + ws0 + 1024) = pack4(Pcb);                              \
    }                                                                        \
    const char* buf = &XpL[(ST) & 1][0];                                     \
    {                                                                        \
      i32x4 a0 = *(const i32x4*)(buf + alane);           /* mt0 s0 */        \
      i32x4 a1 = *(const i32x4*)(buf + 2048 + alane);    /* mt1 s0 */        \
      acc00 = __builtin_amdgcn_mfma_i32_32x32x32_i8(a0, B00, acc00, 0, 0, 0);\
      acc10 = __builtin_amdgcn_mfma_i32_32x32x32_i8(a1, B00, acc10, 0, 0, 0);\
      acc01 = __builtin_amdgcn_mfma_i32_32x32x32_i8(a0, B01, acc01, 0, 0, 0);\
      acc11 = __builtin_amdgcn_mfma_i32_32x32x32_i8(a1, B01, acc11, 0, 0, 0);\
    }                                                                        \
    {                                                                        \
      i32x4 a0 = *(const i32x4*)(buf + 1024 + alane);        /* mt0 s1 */    \
      i32x4 a1 = *(const i32x4*)(buf + 2048 + 1024 + alane); /* mt1 s1 */    \
      acc00 = __builtin_amdgcn_mfma_i32_32x32x32_i8(a0, B10, acc00, 0, 0, 0);\
      acc10 = __builtin_amdgcn_mfma_i32_32x32x32_i8(a1, B10, acc10, 0, 0, 0);\
      acc01 = __builtin_amdgcn_mfma_i32_32x32x32_i8(a0, B11, acc01, 0, 0, 0);\
      acc11 = __builtin_amdgcn_mfma_i32_32x32x32_i8(a1, B11, acc11, 0, 0, 0);\
    }                                                                        \
    barrier_lgkm_only();                                                     \
  } while (0)

#pragma unroll 1
  for (int st = 0; st < NST - 2; st += 2) {
    STAGE_BODY(st,     P1a, P1b, P0a, P0b, true, true);
    STAGE_BODY(st + 1, P0a, P0b, P1a, P1b, true, true);
  }
  STAGE_BODY(NST - 2, P1a, P1b, P0a, P0b, false, true);
  STAGE_BODY(NST - 1, P0a, P0b, P1a, P1b, false, false);
#undef STAGE_BODY

  // ---- epilogue: out = (dot + b - mean) * rsqrt(var+eps) + beta ----
  // D layout (verified): col = tile base + am, row = (r&3)+8*(r>>2)+4*ah (+32mt)
  const int rb = 4 * ah;
#pragma unroll
  for (int h = 0; h < 2; ++h) {
#pragma unroll
    for (int nt = 0; nt < 2; ++nt) {
      const i32x16 A = (h == 0) ? ((nt == 0) ? acc00 : acc01)
                                : ((nt == 0) ? acc10 : acc11);
      const int c = colbase + nt * 32 + am;
      const float bb  = b[c];
      const float mmc = mm[c];
      const float bec = beta[c];
      const float inv = rsqrtf(mv[c] + 1e-3f);
#pragma unroll
      for (int r = 0; r < 16; ++r) {
        const int row = (r & 3) + 8 * (r >> 2) + rb + 32 * h;
        out[(m0 + row) * D_H + c] = ((float)A[r] + bb - mmc) * inv + bec;
      }
    }
  }
}

extern "C" void kernel_launch(void* const* d_in, const int* in_sizes, int n_in,
                              void* d_out, int out_size, void* d_ws, size_t ws_size,
                              hipStream_t stream) {
  const float* X    = (const float*)d_in[0];  // [32768, 2048]
  const float* W    = (const float*)d_in[1];  // [2048, 512]
  const float* b    = (const float*)d_in[2];  // [512]
  const float* beta = (const float*)d_in[3];  // [512]
  const float* mm   = (const float*)d_in[4];  // [512]
  const float* mv   = (const float*)d_in[5];  // [512]
  float* out = (float*)d_out;                 // [32768, 512]

  char* Wf = (char*)d_ws;  // frag-ordered W signs, 1 MB

  pack_wt_kernel<<<dim3(D_IN / 32), dim3(1024), 0, stream>>>(W, Wf);

  const int M = in_sizes[0] / D_IN;  // 32768
  bgemm_kernel<<<dim3(M / BM), dim3(512), 0, stream>>>(X, Wf, b, beta, mm, mv, out);
}

// Round 15
// 88.997 us; speedup vs baseline: 1.1013x; 1.0375x over previous
//
#include <hip/hip_runtime.h>
#include <stdint.h>

#define D_IN 2048
#define D_H  512
#define BM   64
#define NST  16   // stages of 128 k

typedef __attribute__((ext_vector_type(4)))  int i32x4;
typedef __attribute__((ext_vector_type(16))) int i32x16;

// Raw barrier: LDS-only drain (lgkmcnt(0)); vmcnt NOT drained -> the X
// prefetch batch stays in flight across the barrier. (hipcc's __syncthreads
// lowering emits s_waitcnt vmcnt(0) lgkmcnt(0) before s_barrier, emptying
// the HBM queue at every stage top.) Cross-wave state is LDS-only, so
// lgkmcnt(0) is sufficient for correctness (verified R14: passed).
__device__ __forceinline__ void barrier_lgkm_only() {
  asm volatile("s_waitcnt lgkmcnt(0)" ::: "memory");
  __builtin_amdgcn_sched_barrier(0);
  __builtin_amdgcn_s_barrier();
  __builtin_amdgcn_sched_barrier(0);
}

// Wfrag[sg][t][l][16] : byte j = sign(W[sg*32 + 16*(l>>5) + j][t*32 + (l&31)])
// -> every GEMM B-load is 64 lanes x 16B = 1KB contiguous.
__global__ __launch_bounds__(1024) void pack_wt_kernel(
    const float* __restrict__ W, char* __restrict__ Wf) {
  const int s = blockIdx.x;          // 0..63  (k-step)
  const int t = threadIdx.x >> 6;    // 0..15  (col tile)
  const int l = threadIdx.x & 63;    // lane
  const int n = t * 32 + (l & 31);
  const int kbase = s * 32 + 16 * (l >> 5);
  uint wq[4];
#pragma unroll
  for (int q = 0; q < 4; ++q) {
    uint w = 0x01010101u;  // +1 bytes; negative -> XOR 0xFE -> 0xFF (-1)
#pragma unroll
    for (int j = 0; j < 4; ++j) {
      uint bits = __float_as_uint(W[(size_t)(kbase + 4 * q + j) * D_H + n]);
      w ^= ((uint)((int)bits >> 31)) & (0xFEu << (8 * j));
    }
    wq[q] = w;
  }
  *(uint4*)(Wf + ((size_t)(s * 16 + t) * 64 + l) * 16) =
      make_uint4(wq[0], wq[1], wq[2], wq[3]);
}

__device__ __forceinline__ uint pack4(float4 v) {
  uint w = 0x01010101u;
  w ^= ((uint)((int)__float_as_uint(v.x) >> 31)) & 0x000000FEu;
  w ^= ((uint)((int)__float_as_uint(v.y) >> 31)) & 0x0000FE00u;
  w ^= ((uint)((int)__float_as_uint(v.z) >> 31)) & 0x00FE0000u;
  w ^= ((uint)((int)__float_as_uint(v.w) >> 31)) & 0xFE000000u;
  return w;
}

// Binary GEMM via v_mfma_i32_32x32x32_i8. Structure = R10 verbatim (best:
// 88.7 us): 512 thr / 8 waves, 64 rows x 512 cols, wave owns all 64 rows x
// 2 col tiles (4 MFMA/k-step, acc = 4 x i32x16 in AGPRs), 16 stages of 128k,
// depth-1 X prefetch, B-before-X issue order. ONLY change: lgkm-only
// barriers so the X batch issued at stage top survives the stage boundary.
__global__ __launch_bounds__(512) void bgemm_kernel(
    const float* __restrict__ X, const char* __restrict__ Wf,
    const float* __restrict__ b, const float* __restrict__ beta,
    const float* __restrict__ mm, const float* __restrict__ mv,
    float* __restrict__ out) {
  __shared__ __align__(16) char XpL[2][8192];  // 2 x (64 rows x 128 k-bytes)

  const int tid = threadIdx.x;
  const int l   = tid & 63;
  const int wv  = tid >> 6;        // 0..7
  const int am  = l & 31;
  const int ah  = l >> 5;
  const size_t m0 = (size_t)blockIdx.x * BM;
  const int colbase = wv * 64;

  // X loader: thread -> rows r0+{0,16,32,48}, float4 index kw within slice
  const int r0 = tid >> 5;   // 0..15
  const int kw = tid & 31;   // 0..31
  const float* Xt = X + (m0 + r0) * D_IN + kw * 4;

  // LDS write byte offset for row r0 (rows +16i share the key: 16 = 0 mod 8)
  const int ws0 = r0 * 128 + (((kw >> 2) ^ (r0 & 7)) << 4) + (kw & 3) * 4;

  // LDS read: row halves at am and am+32 (same key am&7)
  const int arow0 = am * 128;
  const int arow1 = arow0 + 32 * 128;
  const int akey  = am & 7;

  // B pointers: tiles 2wv, 2wv+1; load for (st,s') at + st*65536 + s'*16384
  const char* Bb0 = Wf + (size_t)(2 * wv) * 1024 + (size_t)l * 16;
  const char* Bb1 = Bb0 + 1024;

  i32x16 acc00, acc01, acc10, acc11;  // [rowhalf][tile]
#pragma unroll
  for (int r = 0; r < 16; ++r) { acc00[r] = 0; acc01[r] = 0; acc10[r] = 0; acc11[r] = 0; }

  float4 vxa, vxb, vxc, vxd;

  // ---- prologue: stage 0 loaded + packed directly ----
  vxa = *(const float4*)(Xt);
  vxb = *(const float4*)(Xt + 16 * D_IN);
  vxc = *(const float4*)(Xt + 32 * D_IN);
  vxd = *(const float4*)(Xt + 48 * D_IN);
  *(uint*)(XpL[0] + ws0)        = pack4(vxa);
  *(uint*)(XpL[0] + ws0 + 2048) = pack4(vxb);
  *(uint*)(XpL[0] + ws0 + 4096) = pack4(vxc);
  *(uint*)(XpL[0] + ws0 + 6144) = pack4(vxd);
  barrier_lgkm_only();

#pragma unroll 1
  for (int st = 0; st < NST; ++st) {
    const char* buf = &XpL[st & 1][0];
    const size_t so = (size_t)st * 65536;

    // 1) all 8 B-loads (oldest in vmcnt; waits on them never touch X)
    i32x4 B0a = *(const i32x4*)(Bb0 + so + 0 * 16384);
    i32x4 B0b = *(const i32x4*)(Bb1 + so + 0 * 16384);
    i32x4 B1a = *(const i32x4*)(Bb0 + so + 1 * 16384);
    i32x4 B1b = *(const i32x4*)(Bb1 + so + 1 * 16384);
    i32x4 B2a = *(const i32x4*)(Bb0 + so + 2 * 16384);
    i32x4 B2b = *(const i32x4*)(Bb1 + so + 2 * 16384);
    i32x4 B3a = *(const i32x4*)(Bb0 + so + 3 * 16384);
    i32x4 B3b = *(const i32x4*)(Bb1 + so + 3 * 16384);

    // 2) X for stage st+1 (youngest; consumed at stage end; rides through
    //    the lgkm-only barrier of the PREVIOUS iteration's end)
    if (st + 1 < NST) {
      const float* xp = Xt + (st + 1) * 128;
      vxa = *(const float4*)(xp);
      vxb = *(const float4*)(xp + 16 * D_IN);
      vxc = *(const float4*)(xp + 32 * D_IN);
      vxd = *(const float4*)(xp + 48 * D_IN);
    }

    // 3) 4 k-steps
    {
      i32x4 a0 = *(const i32x4*)(buf + arow0 + (((0 + ah) ^ akey) << 4));
      i32x4 a1 = *(const i32x4*)(buf + arow1 + (((0 + ah) ^ akey) << 4));
      acc00 = __builtin_amdgcn_mfma_i32_32x32x32_i8(a0, B0a, acc00, 0, 0, 0);
      acc10 = __builtin_amdgcn_mfma_i32_32x32x32_i8(a1, B0a, acc10, 0, 0, 0);
      acc01 = __builtin_amdgcn_mfma_i32_32x32x32_i8(a0, B0b, acc01, 0, 0, 0);
      acc11 = __builtin_amdgcn_mfma_i32_32x32x32_i8(a1, B0b, acc11, 0, 0, 0);
    }
    {
      i32x4 a0 = *(const i32x4*)(buf + arow0 + (((2 + ah) ^ akey) << 4));
      i32x4 a1 = *(const i32x4*)(buf + arow1 + (((2 + ah) ^ akey) << 4));
      acc00 = __builtin_amdgcn_mfma_i32_32x32x32_i8(a0, B1a, acc00, 0, 0, 0);
      acc10 = __builtin_amdgcn_mfma_i32_32x32x32_i8(a1, B1a, acc10, 0, 0, 0);
      acc01 = __builtin_amdgcn_mfma_i32_32x32x32_i8(a0, B1b, acc01, 0, 0, 0);
      acc11 = __builtin_amdgcn_mfma_i32_32x32x32_i8(a1, B1b, acc11, 0, 0, 0);
    }
    {
      i32x4 a0 = *(const i32x4*)(buf + arow0 + (((4 + ah) ^ akey) << 4));
      i32x4 a1 = *(const i32x4*)(buf + arow1 + (((4 + ah) ^ akey) << 4));
      acc00 = __builtin_amdgcn_mfma_i32_32x32x32_i8(a0, B2a, acc00, 0, 0, 0);
      acc10 = __builtin_amdgcn_mfma_i32_32x32x32_i8(a1, B2a, acc10, 0, 0, 0);
      acc01 = __builtin_amdgcn_mfma_i32_32x32x32_i8(a0, B2b, acc01, 0, 0, 0);
      acc11 = __builtin_amdgcn_mfma_i32_32x32x32_i8(a1, B2b, acc11, 0, 0, 0);
    }
    {
      i32x4 a0 = *(const i32x4*)(buf + arow0 + (((6 + ah) ^ akey) << 4));
      i32x4 a1 = *(const i32x4*)(buf + arow1 + (((6 + ah) ^ akey) << 4));
      acc00 = __builtin_amdgcn_mfma_i32_32x32x32_i8(a0, B3a, acc00, 0, 0, 0);
      acc10 = __builtin_amdgcn_mfma_i32_32x32x32_i8(a1, B3a, acc10, 0, 0, 0);
      acc01 = __builtin_amdgcn_mfma_i32_32x32x32_i8(a0, B3b, acc01, 0, 0, 0);
      acc11 = __builtin_amdgcn_mfma_i32_32x32x32_i8(a1, B3b, acc11, 0, 0, 0);
    }

    // 4) pack + write next stage's A tile
    if (st + 1 < NST) {
      char* nbuf = &XpL[(st + 1) & 1][0];
      *(uint*)(nbuf + ws0)        = pack4(vxa);
      *(uint*)(nbuf + ws0 + 2048) = pack4(vxb);
      *(uint*)(nbuf + ws0 + 4096) = pack4(vxc);
      *(uint*)(nbuf + ws0 + 6144) = pack4(vxd);
    }
    barrier_lgkm_only();
  }

  // ---- epilogue: out = (dot + b - mean) * rsqrt(var+eps) + beta ----
  // D layout (verified): col = tile base + am, row = (r&3)+8*(r>>2)+4*ah (+32h)
  const int rb = 4 * ah;
#pragma unroll
  for (int h = 0; h < 2; ++h) {
#pragma unroll
    for (int nt = 0; nt < 2; ++nt) {
      const i32x16 A = (h == 0) ? ((nt == 0) ? acc00 : acc01)
                                : ((nt == 0) ? acc10 : acc11);
      const int c = colbase + nt * 32 + am;
      const float bb  = b[c];
      const float mmc = mm[c];
      const float bec = beta[c];
      const float inv = rsqrtf(mv[c] + 1e-3f);
#pragma unroll
      for (int r = 0; r < 16; ++r) {
        const int row = (r & 3) + 8 * (r >> 2) + rb + 32 * h;
        out[(m0 + row) * D_H + c] = ((float)A[r] + bb - mmc) * inv + bec;
      }
    }
  }
}

extern "C" void kernel_launch(void* const* d_in, const int* in_sizes, int n_in,
                              void* d_out, int out_size, void* d_ws, size_t ws_size,
                              hipStream_t stream) {
  const float* X    = (const float*)d_in[0];  // [32768, 2048]
  const float* W    = (const float*)d_in[1];  // [2048, 512]
  const float* b    = (const float*)d_in[2];  // [512]
  const float* beta = (const float*)d_in[3];  // [512]
  const float* mm   = (const float*)d_in[4];  // [512]
  const float* mv   = (const float*)d_in[5];  // [512]
  float* out = (float*)d_out;                 // [32768, 512]

  char* Wf = (char*)d_ws;  // frag-ordered W signs, 1 MB

  pack_wt_kernel<<<dim3(D_IN / 32), dim3(1024), 0, stream>>>(W, Wf);

  const int M = in_sizes[0] / D_IN;  // 32768
  bgemm_kernel<<<dim3(M / BM), dim3(512), 0, stream>>>(X, Wf, b, beta, mm, mv, out);
}